// Round 1
// baseline (324.529 us; speedup 1.0000x reference)
//
#include <hip/hip_runtime.h>
#include <hip/hip_bf16.h>
#include <stdint.h>

typedef unsigned short u16;
typedef __attribute__((ext_vector_type(8))) short bf16x8;   // 8 bf16 = 4 VGPRs
typedef __attribute__((ext_vector_type(4))) float f32x4;

#define DEV __device__ __forceinline__

DEV u16 f2bf(float f) {
  union { float f; unsigned u; } v; v.f = f;
  unsigned r = (v.u + 0x7fffu + ((v.u >> 16) & 1u)) >> 16;   // RNE
  return (u16)r;
}

DEV f32x4 mfma16(bf16x8 a, bf16x8 b, f32x4 c) {
  return __builtin_amdgcn_mfma_f32_16x16x32_bf16(a, b, c, 0, 0, 0);
}

DEV void gload_lds16(const u16* g, u16* l) {
  __builtin_amdgcn_global_load_lds((const __attribute__((address_space(1))) void*)g,
                                   (__attribute__((address_space(3))) void*)l, 16, 0, 0);
}

// ---------------- fp32 -> bf16 convert ----------------
__global__ void cvt_bf16_kernel(const float* __restrict__ src, u16* __restrict__ dst, int n4) {
  int stride = gridDim.x * blockDim.x;
  for (int i = blockIdx.x * blockDim.x + threadIdx.x; i < n4; i += stride) {
    float4 v = ((const float4*)src)[i];
    ushort4 o; o.x = f2bf(v.x); o.y = f2bf(v.y); o.z = f2bf(v.z); o.w = f2bf(v.w);
    ((ushort4*)dst)[i] = o;
  }
}

// ------------- fp32 [R][C] -> bf16 [C][R] transpose-convert (64x64 tiles) -------------
__global__ void transpose_cvt_kernel(const float* __restrict__ src, u16* __restrict__ dst,
                                     int R, int C, long zSrc, long zDst) {
  __shared__ u16 tile[64][72];   // +8 pad: 2-way max on column reads
  src += (size_t)blockIdx.z * zSrc;
  dst += (size_t)blockIdx.z * zDst;
  int r0 = blockIdx.y * 64, c0 = blockIdx.x * 64;
  int tr = threadIdx.x >> 2, tc = (threadIdx.x & 3) * 16;
  const float* s = src + (size_t)(r0 + tr) * C + c0 + tc;
#pragma unroll
  for (int q = 0; q < 4; ++q) {
    float4 v = ((const float4*)s)[q];
    tile[tr][tc + q * 4 + 0] = f2bf(v.x);
    tile[tr][tc + q * 4 + 1] = f2bf(v.y);
    tile[tr][tc + q * 4 + 2] = f2bf(v.z);
    tile[tr][tc + q * 4 + 3] = f2bf(v.w);
  }
  __syncthreads();
  u16 tmp[16];
#pragma unroll
  for (int i = 0; i < 16; ++i) tmp[i] = tile[tc + i][tr];
  u16* d = dst + (size_t)(c0 + tr) * R + r0 + tc;
  *(bf16x8*)d = *(const bf16x8*)&tmp[0];
  *(bf16x8*)(d + 8) = *(const bf16x8*)&tmp[8];
}

// ------------- GEMM: C[M][N] = A[M][K] * Bt[N][K]^T  (both bf16, row-major, fp32 accum) -------------
// 128x128 tile, BK=32, 4 waves (2x2), each wave 64x64 = 4x4 frags of 16x16x32.
// LDS slot swizzle: phys_slot = (logical_slot + (row>>1)) & 3  -> conflict-free-ish ds_read_b128.
// Staged via global_load_lds(16B, linear dest) with inverse-swizzled global source.
template<bool FP32OUT>
__global__ __launch_bounds__(256, 2)
void gemm_bt_kernel(const u16* __restrict__ A, const u16* __restrict__ Bt,
                    void* __restrict__ Cout, const float* __restrict__ bias,
                    int M, int N, int K, long zA, long zB, long zC) {
  __shared__ __align__(16) u16 smA[128 * 32];
  __shared__ __align__(16) u16 smB[128 * 32];
  const int t = threadIdx.x;
  const int lane = t & 63, wave = t >> 6;
  const int wm = wave & 1, wn = wave >> 1;
  const int g = lane >> 4, r = lane & 15;
  const int z = blockIdx.z;
  const u16* Ab = A + (size_t)z * zA;
  const u16* Bb = Bt + (size_t)z * zB;
  const int m0 = blockIdx.y * 128, n0 = blockIdx.x * 128;
  const int srow = t >> 2;

  f32x4 acc[4][4];
#pragma unroll
  for (int m = 0; m < 4; ++m)
#pragma unroll
    for (int n = 0; n < 4; ++n) acc[m][n] = f32x4{0.f, 0.f, 0.f, 0.f};

  for (int k0 = 0; k0 < K; k0 += 32) {
#pragma unroll
    for (int p = 0; p < 2; ++p) {
      int row = p * 64 + srow;
      int ls = ((t & 3) + 4 - ((row >> 1) & 3)) & 3;   // inverse swizzle on global source
      const u16* ga = Ab + (size_t)(m0 + row) * K + k0 + ls * 8;
      const u16* gb = Bb + (size_t)(n0 + row) * K + k0 + ls * 8;
      gload_lds16(ga, smA + p * 2048 + wave * 512);
      gload_lds16(gb, smB + p * 2048 + wave * 512);
    }
    __syncthreads();
    bf16x8 af[4], bfr[4];
#pragma unroll
    for (int m = 0; m < 4; ++m) {
      int row = wm * 64 + m * 16 + r;
      int ps = (g + (row >> 1)) & 3;
      af[m] = *(const bf16x8*)&smA[row * 32 + ps * 8];
    }
#pragma unroll
    for (int n = 0; n < 4; ++n) {
      int row = wn * 64 + n * 16 + r;
      int ps = (g + (row >> 1)) & 3;
      bfr[n] = *(const bf16x8*)&smB[row * 32 + ps * 8];
    }
#pragma unroll
    for (int m = 0; m < 4; ++m)
#pragma unroll
      for (int n = 0; n < 4; ++n)
        acc[m][n] = mfma16(af[m], bfr[n], acc[m][n]);
    __syncthreads();
  }

  // epilogue: C row = (lane>>4)*4+reg, col = lane&15  [m89-verified layout]
  if constexpr (FP32OUT) {
    float* C = (float*)Cout + (size_t)z * zC;
#pragma unroll
    for (int n = 0; n < 4; ++n) {
      int col = n0 + wn * 64 + n * 16 + r;
      float bv = bias[col];
#pragma unroll
      for (int m = 0; m < 4; ++m) {
        int rowb = m0 + wm * 64 + m * 16 + 4 * g;
#pragma unroll
        for (int rr = 0; rr < 4; ++rr)
          C[(size_t)(rowb + rr) * N + col] = acc[m][n][rr] + bv;
      }
    }
  } else {
    u16* C = (u16*)Cout + (size_t)z * zC;
#pragma unroll
    for (int n = 0; n < 4; ++n) {
      int col = n0 + wn * 64 + n * 16 + r;
#pragma unroll
      for (int m = 0; m < 4; ++m) {
        int rowb = m0 + wm * 64 + m * 16 + 4 * g;
#pragma unroll
        for (int rr = 0; rr < 4; ++rr)
          C[(size_t)(rowb + rr) * N + col] = f2bf(acc[m][n][rr]);
      }
    }
  }
}

// ------------- fused attention: dots -> softmax -> PV, per (b, h, 64-row Q tile) -------------
// Q[16384][1024] bf16, Klow/Vlow[4][256][1024] bf16, Out[16384][1024] bf16.
// 4 waves x 16 Q-rows. K staged in LDS (8-slot rotation swizzle); V transposed into LDS;
// P (softmax probs) round-trips through XOR-swizzled LDS.
__global__ __launch_bounds__(256, 2)
void attn_kernel(const u16* __restrict__ Q, const u16* __restrict__ Kl,
                 const u16* __restrict__ Vl, u16* __restrict__ Out) {
  __shared__ __align__(16) u16 smKV[256 * 64];  // K tile, later reused as VT[64][256]
  __shared__ __align__(16) u16 smP[64 * 256];   // P tile [64 rows][256 k]
  const int t = threadIdx.x, lane = t & 63, w = t >> 6;
  const int g = lane >> 4, r = lane & 15;
  const int b = blockIdx.z, h = blockIdx.y, n0 = blockIdx.x * 64;
  const u16* Kb = Kl + (size_t)b * 256 * 1024 + h * 64;
  const u16* Vb = Vl + (size_t)b * 256 * 1024 + h * 64;

  // stage K[256][64] with slot rotation: phys_slot = (logical + row) & 7
#pragma unroll
  for (int p = 0; p < 8; ++p) {
    int row = p * 32 + (t >> 3);
    int ls = ((t & 7) + 8 - (row & 7)) & 7;
    gload_lds16(Kb + (size_t)row * 1024 + ls * 8, smKV + p * 2048 + w * 512);
  }
  // Q fragments straight from global (read exactly once)
  int qrow = n0 + w * 16 + r;
  const u16* Qp = Q + ((size_t)(b * 4096 + qrow)) * 1024 + h * 64 + g * 8;
  bf16x8 aq0 = *(const bf16x8*)Qp;
  bf16x8 aq1 = *(const bf16x8*)(Qp + 32);
  __syncthreads();

  // dots[16 frags][4 rows]: QK^T over dh=64 (2 MFMA K-steps)
  f32x4 dotv[16];
#pragma unroll
  for (int kf = 0; kf < 16; ++kf) {
    int row = kf * 16 + r;
    bf16x8 kb0 = *(const bf16x8*)&smKV[row * 64 + ((g + row) & 7) * 8];
    bf16x8 kb1 = *(const bf16x8*)&smKV[row * 64 + ((4 + g + row) & 7) * 8];
    f32x4 d = f32x4{0.f, 0.f, 0.f, 0.f};
    d = mfma16(aq0, kb0, d);
    d = mfma16(aq1, kb1, d);
    dotv[kf] = d;
  }

  // softmax over 256 (16 in-lane frags x 16-lane butterfly), write P bf16 to swizzled LDS
  float rsum[4];
#pragma unroll
  for (int rr = 0; rr < 4; ++rr) {
    float m = dotv[0][rr];
#pragma unroll
    for (int kf = 1; kf < 16; ++kf) m = fmaxf(m, dotv[kf][rr]);
#pragma unroll
    for (int mask = 1; mask < 16; mask <<= 1) m = fmaxf(m, __shfl_xor(m, mask, 64));
    int prow = w * 16 + 4 * g + rr;
    float s = 0.f;
#pragma unroll
    for (int kf = 0; kf < 16; ++kf) {
      float p = __expf((dotv[kf][rr] - m) * 0.125f);   // scale dh^-0.5 folded in
      s += p;
      int idx = (prow * 256 + kf * 16 + r) ^ ((prow & 7) << 3);
      smP[idx] = f2bf(p);
    }
#pragma unroll
    for (int mask = 1; mask < 16; mask <<= 1) s += __shfl_xor(s, mask, 64);
    rsum[rr] = 1.f / s;
  }
  __syncthreads();   // all waves done reading K

  // transpose V into smKV as VT[64][256] (XOR swizzle on u16 index)
  {
    int k = t;
#pragma unroll
    for (int c8 = 0; c8 < 8; ++c8) {
      bf16x8 v = *(const bf16x8*)(Vb + (size_t)k * 1024 + c8 * 8);
#pragma unroll
      for (int j = 0; j < 8; ++j) {
        int d = c8 * 8 + j;
        int idx = (d * 256 + k) ^ ((d & 7) << 3);
        smKV[idx] = (u16)v[j];
      }
    }
  }
  __syncthreads();

  // PV: out[16 rows][64] = P[16][256] @ V[256][64], 8 K-steps
  f32x4 oacc[4];
#pragma unroll
  for (int df = 0; df < 4; ++df) oacc[df] = f32x4{0.f, 0.f, 0.f, 0.f};
#pragma unroll
  for (int kk = 0; kk < 8; ++kk) {
    int prow = w * 16 + r;
    bf16x8 ap = *(const bf16x8*)&smP[(prow * 256 + kk * 32 + g * 8) ^ ((prow & 7) << 3)];
#pragma unroll
    for (int df = 0; df < 4; ++df) {
      int vrow = df * 16 + r;
      bf16x8 bv = *(const bf16x8*)&smKV[(vrow * 256 + kk * 32 + g * 8) ^ ((vrow & 7) << 3)];
      oacc[df] = mfma16(ap, bv, oacc[df]);
    }
  }
#pragma unroll
  for (int df = 0; df < 4; ++df)
#pragma unroll
    for (int rr = 0; rr < 4; ++rr) {
      int orow = n0 + w * 16 + 4 * g + rr;
      int ocol = h * 64 + df * 16 + r;
      Out[((size_t)(b * 4096 + orow)) * 1024 + ocol] = f2bf(oacc[df][rr] * rsum[rr]);
    }
}

extern "C" void kernel_launch(void* const* d_in, const int* in_sizes, int n_in,
                              void* d_out, int out_size, void* d_ws, size_t ws_size,
                              hipStream_t stream) {
  const float* x  = (const float*)d_in[0];
  const float* Wq = (const float*)d_in[1];
  const float* Wk = (const float*)d_in[2];
  const float* Wv = (const float*)d_in[3];
  const float* pk = (const float*)d_in[4];
  const float* pv = (const float*)d_in[5];
  const float* Wo = (const float*)d_in[6];
  const float* bo = (const float*)d_in[7];

  u16* ws = (u16*)d_ws;
  u16* xbf   = ws;                   // [16384][1024]
  u16* xT    = xbf + 16777216;       // [4][1024][4096]
  u16* wqb   = xT + 16777216;        // [1024][1024]
  u16* wkb   = wqb + 1048576;
  u16* wvb   = wkb + 1048576;
  u16* wob   = wvb + 1048576;
  u16* projT = wob + 1048576;        // [2][256][4096] (k then v)
  u16* Qb    = projT + 2097152;      // [16384][1024]
  u16* xp    = Qb + 16777216;        // [4][512][1024] (rows 0-255 = k, 256-511 = v)
  u16* klow  = xp + 2097152;         // [4][256][1024]
  u16* vlow  = klow + 1048576;       // [4][256][1024]
  u16* aout  = xbf;                  // reuse: xbf dead after Q GEMM

  // converts
  cvt_bf16_kernel<<<2048, 256, 0, stream>>>(x, xbf, 16777216 / 4);
  cvt_bf16_kernel<<<512, 256, 0, stream>>>(Wq, wqb, 1048576 / 4);
  cvt_bf16_kernel<<<512, 256, 0, stream>>>(Wk, wkb, 1048576 / 4);
  cvt_bf16_kernel<<<512, 256, 0, stream>>>(Wv, wvb, 1048576 / 4);
  cvt_bf16_kernel<<<512, 256, 0, stream>>>(Wo, wob, 1048576 / 4);
  // transposes: x -> xT (per batch), proj_k/proj_v -> projT
  transpose_cvt_kernel<<<dim3(16, 64, 4), 256, 0, stream>>>(x, xT, 4096, 1024, 4194304, 4194304);
  transpose_cvt_kernel<<<dim3(4, 64, 1), 256, 0, stream>>>(pk, projT, 4096, 256, 0, 0);
  transpose_cvt_kernel<<<dim3(4, 64, 1), 256, 0, stream>>>(pv, projT + 1048576, 4096, 256, 0, 0);
  // Q = x @ Wq^T        [16384,1024,1024]
  gemm_bt_kernel<false><<<dim3(8, 128, 1), 256, 0, stream>>>(xbf, wqb, (void*)Qb, nullptr,
                                                             16384, 1024, 1024, 0, 0, 0);
  // xp[b] = projT @ xT[b]   [512,1024,4096], z=batch
  gemm_bt_kernel<false><<<dim3(8, 4, 4), 256, 0, stream>>>(projT, xT, (void*)xp, nullptr,
                                                           512, 1024, 4096, 0, 4194304, 524288);
  // keys_low[b] = xp_k[b] @ Wk^T   [256,1024,1024], z=batch
  gemm_bt_kernel<false><<<dim3(8, 2, 4), 256, 0, stream>>>(xp, wkb, (void*)klow, nullptr,
                                                           256, 1024, 1024, 524288, 0, 262144);
  // vals_low[b] = xp_v[b] @ Wv^T
  gemm_bt_kernel<false><<<dim3(8, 2, 4), 256, 0, stream>>>(xp + 262144, wvb, (void*)vlow, nullptr,
                                                           256, 1024, 1024, 524288, 0, 262144);
  // attention
  attn_kernel<<<dim3(64, 16, 4), 256, 0, stream>>>(Qb, klow, vlow, aout);
  // final = attn_out @ Wo^T + bo   -> fp32 d_out
  gemm_bt_kernel<true><<<dim3(8, 128, 1), 256, 0, stream>>>(aout, wob, d_out, bo,
                                                            16384, 1024, 1024, 0, 0, 0);
}

// Round 2
// 241.951 us; speedup vs baseline: 1.3413x; 1.3413x over previous
//
#include <hip/hip_runtime.h>
#include <hip/hip_bf16.h>
#include <stdint.h>

typedef unsigned short u16;
typedef __attribute__((ext_vector_type(8))) short bf16x8;   // 8 bf16 = 4 VGPRs
typedef __attribute__((ext_vector_type(4))) float f32x4;

#define DEV __device__ __forceinline__

DEV u16 f2bf(float f) {
  union { float f; unsigned u; } v; v.f = f;
  unsigned r = (v.u + 0x7fffu + ((v.u >> 16) & 1u)) >> 16;   // RNE
  return (u16)r;
}

DEV f32x4 mfma16(bf16x8 a, bf16x8 b, f32x4 c) {
  return __builtin_amdgcn_mfma_f32_16x16x32_bf16(a, b, c, 0, 0, 0);
}

DEV void gload_lds16(const u16* g, u16* l) {
  __builtin_amdgcn_global_load_lds((const __attribute__((address_space(1))) void*)g,
                                   (__attribute__((address_space(3))) void*)l, 16, 0, 0);
}

// ---------------- fused fp32 -> bf16 convert (+ optional row-major copy) + transpose ----------------
// src [R][C] fp32 -> dst_rm [R][C] bf16 (if non-null), dst_tp [C][R] bf16.
__global__ void cvt_xpose_kernel(const float* __restrict__ src, u16* __restrict__ dst_rm,
                                 u16* __restrict__ dst_tp, int R, int C,
                                 long zS, long zRM, long zTP) {
  __shared__ u16 tile[64][72];
  src += (size_t)blockIdx.z * zS;
  dst_tp += (size_t)blockIdx.z * zTP;
  int r0 = blockIdx.y * 64, c0 = blockIdx.x * 64;
  int tr = threadIdx.x >> 2, tc = (threadIdx.x & 3) * 16;
  const float* s = src + (size_t)(r0 + tr) * C + c0 + tc;
  u16 loc[16];
#pragma unroll
  for (int q = 0; q < 4; ++q) {
    float4 v = ((const float4*)s)[q];
    loc[q * 4 + 0] = f2bf(v.x); loc[q * 4 + 1] = f2bf(v.y);
    loc[q * 4 + 2] = f2bf(v.z); loc[q * 4 + 3] = f2bf(v.w);
  }
#pragma unroll
  for (int i = 0; i < 16; ++i) tile[tr][tc + i] = loc[i];
  if (dst_rm) {
    u16* d = dst_rm + (size_t)blockIdx.z * zRM + (size_t)(r0 + tr) * C + c0 + tc;
    *(bf16x8*)d = *(const bf16x8*)&loc[0];
    *(bf16x8*)(d + 8) = *(const bf16x8*)&loc[8];
  }
  __syncthreads();
  u16 tmp[16];
#pragma unroll
  for (int i = 0; i < 16; ++i) tmp[i] = tile[tc + i][tr];
  u16* d = dst_tp + (size_t)(c0 + tr) * R + r0 + tc;
  *(bf16x8*)d = *(const bf16x8*)&tmp[0];
  *(bf16x8*)(d + 8) = *(const bf16x8*)&tmp[8];
}

// ---------------- 4 weight matrices fp32->bf16 in one launch ----------------
__global__ void cvt_w4_kernel(const float* __restrict__ s0, const float* __restrict__ s1,
                              const float* __restrict__ s2, const float* __restrict__ s3,
                              u16* __restrict__ d0, u16* __restrict__ d1,
                              u16* __restrict__ d2, u16* __restrict__ d3) {
  const float* s; u16* d;
  switch (blockIdx.y) {
    case 0: s = s0; d = d0; break;
    case 1: s = s1; d = d1; break;
    case 2: s = s2; d = d2; break;
    default: s = s3; d = d3; break;
  }
  int i = blockIdx.x * 256 + threadIdx.x;          // 262144 float4 per matrix
  float4 v = ((const float4*)s)[i];
  ushort4 o; o.x = f2bf(v.x); o.y = f2bf(v.y); o.z = f2bf(v.z); o.w = f2bf(v.w);
  ((ushort4*)d)[i] = o;
}

// ---------------- split-K reduce: out_bf16[i] = sum_{kc<4} part_f32[i + kc*stride] ----------------
__global__ void reduce4_kernel(const float* __restrict__ part, u16* __restrict__ out) {
  int i = blockIdx.x * 256 + threadIdx.x;          // float4 index, n4 = 524288
  const float4* p = (const float4*)part;
  float4 a = p[i], b = p[i + 524288], c = p[i + 1048576], d = p[i + 1572864];
  ushort4 o;
  o.x = f2bf(a.x + b.x + c.x + d.x);
  o.y = f2bf(a.y + b.y + c.y + d.y);
  o.z = f2bf(a.z + b.z + c.z + d.z);
  o.w = f2bf(a.w + b.w + c.w + d.w);
  ((ushort4*)out)[i] = o;
}

// ------------- GEMM: C = A[M][K] * Bt[N][K]^T, bf16 in, fp32 accum -------------
// 128x128 tile, BK=32, 4 waves. Double-buffered LDS: prefetch tile t+1 issued before
// compute of tile t; single __syncthreads per iter (drains vmcnt+lgkm) => load latency
// overlaps ds_read+MFMA.  LDS slot swizzle: phys = (slot + (row>>1)) & 3 (2-way max).
// XCD swizzle (gx==8 assumed): 8 consecutive blocks (sharing A-panel) -> same XCD L2.
// OMODE: 0 = bf16 out, 1 = fp32 + bias, 2 = fp32 raw (split-K partial).
// z decomposition: b = z % bMod, kc = z / bMod; A += b*zA + kc*kChunk; B likewise;
// C += z*zC.  If Bt2 != null, B-matrix selects by (b & 1).
template<int OMODE>
__global__ __launch_bounds__(256, 3)
void gemm_bt_kernel(const u16* __restrict__ A, const u16* __restrict__ Bt,
                    const u16* __restrict__ Bt2, void* __restrict__ Cout,
                    const float* __restrict__ bias,
                    int ldA, int ldB, int ldC, int Klen,
                    long zA, long zB, long zC, int bMod, long kChunk) {
  __shared__ __align__(16) u16 smA[2][128 * 32];
  __shared__ __align__(16) u16 smB[2][128 * 32];
  const int t = threadIdx.x;
  const int lane = t & 63, wave = t >> 6;
  const int wm = wave & 1, wn = wave >> 1;
  const int g = lane >> 4, r = lane & 15;
  // XCD-aware swizzle (gx == 8)
  const int id = (blockIdx.y << 3) | blockIdx.x;
  const int s = (id & 7) * gridDim.y + (id >> 3);
  const int bx = s & 7, by = s >> 3;
  const int z = blockIdx.z;
  const int b = z % bMod, kc = z / bMod;
  const u16* Ab = A + (size_t)b * zA + (size_t)kc * kChunk;
  const u16* Bbase = (Bt2 && (b & 1)) ? Bt2 : Bt;
  const u16* Bb = Bbase + (size_t)b * zB + (size_t)kc * kChunk;
  const int m0 = by * 128, n0 = bx * 128;
  const int srow = t >> 2;
  const int lslot = ((t & 3) + 4 - ((srow >> 1) & 3)) & 3;  // inverse swizzle on global src

  f32x4 acc[4][4];
#pragma unroll
  for (int m = 0; m < 4; ++m)
#pragma unroll
    for (int n = 0; n < 4; ++n) acc[m][n] = f32x4{0.f, 0.f, 0.f, 0.f};

  auto STAGE = [&](int buf, int k0) {
#pragma unroll
    for (int p = 0; p < 2; ++p) {
      int row = p * 64 + srow;
      // (row>>1)&3 differs from srow's only via p*64 which is mult of 32 -> same; lslot valid for both p
      gload_lds16(Ab + (size_t)(m0 + row) * ldA + k0 + lslot * 8, &smA[buf][p * 2048 + wave * 512]);
      gload_lds16(Bb + (size_t)(n0 + row) * ldB + k0 + lslot * 8, &smB[buf][p * 2048 + wave * 512]);
    }
  };

  const int nt = Klen >> 5;
  STAGE(0, 0);
  __syncthreads();
  int cur = 0;
  for (int it = 0; it < nt; ++it) {
    if (it + 1 < nt) STAGE(cur ^ 1, (it + 1) << 5);   // prefetch overlaps compute below
    bf16x8 af[4], bfr[4];
#pragma unroll
    for (int m = 0; m < 4; ++m) {
      int row = wm * 64 + m * 16 + r;
      int ps = (g + (row >> 1)) & 3;
      af[m] = *(const bf16x8*)&smA[cur][row * 32 + ps * 8];
    }
#pragma unroll
    for (int n = 0; n < 4; ++n) {
      int row = wn * 64 + n * 16 + r;
      int ps = (g + (row >> 1)) & 3;
      bfr[n] = *(const bf16x8*)&smB[cur][row * 32 + ps * 8];
    }
#pragma unroll
    for (int m = 0; m < 4; ++m)
#pragma unroll
      for (int n = 0; n < 4; ++n)
        acc[m][n] = mfma16(af[m], bfr[n], acc[m][n]);
    __syncthreads();   // drains vmcnt(0): prefetched tile ready; all reads of cur done
    cur ^= 1;
  }

  // epilogue: C row = (lane>>4)*4+reg, col = lane&15
  if constexpr (OMODE == 0) {
    u16* C = (u16*)Cout + (size_t)z * zC;
#pragma unroll
    for (int n = 0; n < 4; ++n) {
      int col = n0 + wn * 64 + n * 16 + r;
#pragma unroll
      for (int m = 0; m < 4; ++m) {
        int rowb = m0 + wm * 64 + m * 16 + 4 * g;
#pragma unroll
        for (int rr = 0; rr < 4; ++rr)
          C[(size_t)(rowb + rr) * ldC + col] = f2bf(acc[m][n][rr]);
      }
    }
  } else {
    float* C = (float*)Cout + (size_t)z * zC;
#pragma unroll
    for (int n = 0; n < 4; ++n) {
      int col = n0 + wn * 64 + n * 16 + r;
      float bv = (OMODE == 1) ? bias[col] : 0.f;
#pragma unroll
      for (int m = 0; m < 4; ++m) {
        int rowb = m0 + wm * 64 + m * 16 + 4 * g;
#pragma unroll
        for (int rr = 0; rr < 4; ++rr)
          C[(size_t)(rowb + rr) * ldC + col] = acc[m][n][rr] + bv;
      }
    }
  }
}

// ------------- fused attention: dots -> softmax -> PV, per (b, h, 64-row Q tile) -------------
__global__ __launch_bounds__(256, 2)
void attn_kernel(const u16* __restrict__ Q, const u16* __restrict__ Kl,
                 const u16* __restrict__ Vl, u16* __restrict__ Out) {
  __shared__ __align__(16) u16 smKV[256 * 64];  // K tile, later reused as VT[64][256]
  __shared__ __align__(16) u16 smP[64 * 256];   // P tile [64 rows][256 k]
  const int t = threadIdx.x, lane = t & 63, w = t >> 6;
  const int g = lane >> 4, r = lane & 15;
  // XCD swizzle: gx=64, group 8 consecutive n-tiles (sharing KV head) per XCD
  const int id = (blockIdx.y << 6) | blockIdx.x;
  const int s = (id & 7) * (gridDim.y << 3) + (id >> 3);
  const int b = blockIdx.z, h = s >> 6, n0 = (s & 63) * 64;
  const u16* Kb = Kl + (size_t)b * 524288 + h * 64;
  const u16* Vb = Vl + (size_t)b * 524288 + h * 64;

  // stage K[256][64], slot rotation phys = (logical + row) & 7
#pragma unroll
  for (int p = 0; p < 8; ++p) {
    int row = p * 32 + (t >> 3);
    int ls = ((t & 7) + 8 - (row & 7)) & 7;
    gload_lds16(Kb + (size_t)row * 1024 + ls * 8, smKV + p * 2048 + w * 512);
  }
  int qrow = n0 + w * 16 + r;
  const u16* Qp = Q + ((size_t)(b * 4096 + qrow)) * 1024 + h * 64 + g * 8;
  bf16x8 aq0 = *(const bf16x8*)Qp;
  bf16x8 aq1 = *(const bf16x8*)(Qp + 32);
  __syncthreads();

  f32x4 dotv[16];
#pragma unroll
  for (int kf = 0; kf < 16; ++kf) {
    int row = kf * 16 + r;
    bf16x8 kb0 = *(const bf16x8*)&smKV[row * 64 + ((g + row) & 7) * 8];
    bf16x8 kb1 = *(const bf16x8*)&smKV[row * 64 + ((4 + g + row) & 7) * 8];
    f32x4 d = f32x4{0.f, 0.f, 0.f, 0.f};
    d = mfma16(aq0, kb0, d);
    d = mfma16(aq1, kb1, d);
    dotv[kf] = d;
  }

  float rsum[4];
#pragma unroll
  for (int rr = 0; rr < 4; ++rr) {
    float m = dotv[0][rr];
#pragma unroll
    for (int kf = 1; kf < 16; ++kf) m = fmaxf(m, dotv[kf][rr]);
#pragma unroll
    for (int mask = 1; mask < 16; mask <<= 1) m = fmaxf(m, __shfl_xor(m, mask, 64));
    int prow = w * 16 + 4 * g + rr;
    float ssum = 0.f;
#pragma unroll
    for (int kf = 0; kf < 16; ++kf) {
      float p = __expf((dotv[kf][rr] - m) * 0.125f);
      ssum += p;
      int idx = (prow * 256 + kf * 16 + r) ^ ((prow & 7) << 3);
      smP[idx] = f2bf(p);
    }
#pragma unroll
    for (int mask = 1; mask < 16; mask <<= 1) ssum += __shfl_xor(ssum, mask, 64);
    rsum[rr] = 1.f / ssum;
  }
  __syncthreads();

  // transpose V into smKV as VT[64][256] (XOR swizzle)
  {
    int k = t;
#pragma unroll
    for (int c8 = 0; c8 < 8; ++c8) {
      bf16x8 v = *(const bf16x8*)(Vb + (size_t)k * 1024 + c8 * 8);
#pragma unroll
      for (int j = 0; j < 8; ++j) {
        int d = c8 * 8 + j;
        int idx = (d * 256 + k) ^ ((d & 7) << 3);
        smKV[idx] = (u16)v[j];
      }
    }
  }
  __syncthreads();

  f32x4 oacc[4];
#pragma unroll
  for (int df = 0; df < 4; ++df) oacc[df] = f32x4{0.f, 0.f, 0.f, 0.f};
#pragma unroll
  for (int kk = 0; kk < 8; ++kk) {
    int prow = w * 16 + r;
    bf16x8 ap = *(const bf16x8*)&smP[(prow * 256 + kk * 32 + g * 8) ^ ((prow & 7) << 3)];
#pragma unroll
    for (int df = 0; df < 4; ++df) {
      int vrow = df * 16 + r;
      bf16x8 bv = *(const bf16x8*)&smKV[(vrow * 256 + kk * 32 + g * 8) ^ ((vrow & 7) << 3)];
      oacc[df] = mfma16(ap, bv, oacc[df]);
    }
  }
#pragma unroll
  for (int df = 0; df < 4; ++df)
#pragma unroll
    for (int rr = 0; rr < 4; ++rr) {
      int orow = n0 + w * 16 + 4 * g + rr;
      int ocol = h * 64 + df * 16 + r;
      Out[((size_t)(b * 4096 + orow)) * 1024 + ocol] = f2bf(oacc[df][rr] * rsum[rr]);
    }
}

extern "C" void kernel_launch(void* const* d_in, const int* in_sizes, int n_in,
                              void* d_out, int out_size, void* d_ws, size_t ws_size,
                              hipStream_t stream) {
  const float* x  = (const float*)d_in[0];
  const float* Wq = (const float*)d_in[1];
  const float* Wk = (const float*)d_in[2];
  const float* Wv = (const float*)d_in[3];
  const float* pk = (const float*)d_in[4];
  const float* pv = (const float*)d_in[5];
  const float* Wo = (const float*)d_in[6];
  const float* bo = (const float*)d_in[7];

  u16* ws = (u16*)d_ws;
  u16* xbf   = ws;                   // [4][4096][1024] bf16
  u16* xT    = xbf + 16777216;       // [4][1024][4096] bf16
  u16* wqb   = xT + 16777216;        // [1024][1024]
  u16* wkb   = wqb + 1048576;
  u16* wvb   = wkb + 1048576;
  u16* wob   = wvb + 1048576;
  u16* projT = wob + 1048576;        // [2][256][4096]  (k then v)
  u16* Qb    = projT + 2097152;      // [16384][1024] bf16; ALSO holds xp fp32 partials first
  u16* xp    = Qb + 16777216;        // [4][512][1024]  (rows 0-255 k-proj, 256-511 v-proj)
  u16* kvlow = xp + 2097152;         // [4][2][256][1024]  (K then V per batch)
  u16* aout  = xbf;                  // reuse after Q GEMM
  float* xp_part = (float*)Qb;       // [4 kc][4 b][512][1024] fp32 = 33.5 MB (fits Qb exactly)

  // 1) x: convert + row-major bf16 + transpose, one read of x
  cvt_xpose_kernel<<<dim3(16, 64, 4), 256, 0, stream>>>(x, xbf, xT, 4096, 1024,
                                                        4194304, 4194304, 4194304);
  // 2) weights
  cvt_w4_kernel<<<dim3(1024, 4), 256, 0, stream>>>(Wq, Wk, Wv, Wo, wqb, wkb, wvb, wob);
  // 3) proj_k / proj_v transposes
  cvt_xpose_kernel<<<dim3(4, 64, 1), 256, 0, stream>>>(pk, nullptr, projT, 4096, 256, 0, 0, 0);
  cvt_xpose_kernel<<<dim3(4, 64, 1), 256, 0, stream>>>(pv, nullptr, projT + 1048576, 4096, 256, 0, 0, 0);
  // 4) xp partials: split-K x4.  z = kc*4 + b.  A=projT[512][4096], B=xT[b][1024][4096]
  gemm_bt_kernel<2><<<dim3(8, 4, 16), 256, 0, stream>>>(
      projT, xT, nullptr, (void*)xp_part, nullptr,
      4096, 4096, 1024, 1024, 0, 4194304, 524288, 4, 1024);
  // 5) reduce partials -> xp bf16
  reduce4_kernel<<<2048, 256, 0, stream>>>(xp_part, xp);
  // 6) klow/vlow merged: z=0..7, b=z>>1 half=z&1; A = xp + z*262144; B = (z&1)? Wv : Wk
  gemm_bt_kernel<0><<<dim3(8, 2, 8), 256, 0, stream>>>(
      xp, wkb, wvb, (void*)kvlow, nullptr,
      1024, 1024, 1024, 1024, 262144, 0, 262144, 8, 0);
  // 7) Q = x @ Wq^T   (xp_part region now dead -> Qb free)
  gemm_bt_kernel<0><<<dim3(8, 128, 1), 256, 0, stream>>>(
      xbf, wqb, nullptr, (void*)Qb, nullptr,
      1024, 1024, 1024, 1024, 0, 0, 0, 1, 0);
  // 8) attention
  attn_kernel<<<dim3(64, 16, 4), 256, 0, stream>>>(Qb, kvlow, kvlow + 262144, aout);
  // 9) final = attn_out @ Wo^T + bo -> fp32 d_out
  gemm_bt_kernel<1><<<dim3(8, 128, 1), 256, 0, stream>>>(
      aout, wob, nullptr, d_out, bo,
      1024, 1024, 1024, 1024, 0, 0, 0, 1, 0);
}